// Round 16
// baseline (719.840 us; speedup 1.0000x reference)
//
#include <hip/hip_runtime.h>
#include <hip/hip_bf16.h>
#include <math.h>

// ---------------------------------------------------------------------------
// Quantized CNN forward (bitwise-exact vs fp32 reference):
//   block_k: maxpool2( quant_act( conv3x3(x, quant_weight(wk)), ak ) )
//   then global max over HxW, then 1x1 conv (10x128).
// Sparse formulation (R7+, absmax 0.0): ternary weights ~96% zero; skipping
// all-zero (co,ci) pairs is bitwise-safe; per-co accumulation (ci asc, k asc).
//
// R16: R7-R15 all plateaued at 160-220us/conv on the SAME structure: LDS
// staging with 2 barriers/chunk (load->ds_write->barrier->ds_read). R15's
// smaller tile traded staging for HBM fragmentation (FETCH 61->80MB: 8px=32B
// partial-line writes -> RFO; 18-wide rows split lines). This round removes
// LDS AND barriers entirely: each thread loads its own 4x4 patch per ci
// directly from global (4x dwordx4, 4B-aligned is legal). Spatial reuse via
// L1 (lane overlap) and L2 (co-slice re-reads). Block = 16x16 pooled tile
// (full 64B-line writes), wave-slice per blockIdx.z (scalar masks/coefs).
// Bodies = R12 mask-guarded dense 36-FMA; order unchanged -> absmax 0.0.
// ---------------------------------------------------------------------------

typedef float vfloat4 __attribute__((ext_vector_type(4), aligned(4)));

__global__ __launch_bounds__(64)
void prep_zero(unsigned* __restrict__ maxb) {
    if (threadIdx.x < 4) maxb[threadIdx.x] = 0u;
}

__global__ __launch_bounds__(256)
void prep_absmax(const float* __restrict__ w1, const float* __restrict__ w2,
                 const float* __restrict__ w3, const float* __restrict__ wc,
                 unsigned* __restrict__ maxb) {
    const float* srcs[4] = {w1, w2, w3, wc};
    const int    ns[4]   = {32*3*9, 64*32*9, 128*64*9, 10*128};
    const int t = blockIdx.y;
    const float* s = srcs[t];
    const int    N = ns[t];
    float m = 0.f;
    for (int i = blockIdx.x * 256 + threadIdx.x; i < N; i += 16 * 256)
        m = fmaxf(m, fabsf(s[i]));
    #pragma unroll
    for (int o = 32; o > 0; o >>= 1) m = fmaxf(m, __shfl_down(m, o));
    __shared__ float red[4];
    const int lane = threadIdx.x & 63, wid = threadIdx.x >> 6;
    if (lane == 0) red[wid] = m;
    __syncthreads();
    if (threadIdx.x == 0) {
        float mm = fmaxf(fmaxf(red[0], red[1]), fmaxf(red[2], red[3]));
        atomicMax(maxb + t, __float_as_uint(mm));  // |w|>=0: uint order == float order
    }
}

__global__ __launch_bounds__(256)
void prep_quant(const float* __restrict__ w1, const float* __restrict__ w2,
                const float* __restrict__ w3, const float* __restrict__ wc,
                const unsigned* __restrict__ maxb,
                float* __restrict__ q1, float* __restrict__ q2,
                float* __restrict__ q3, float* __restrict__ qc) {
    const float* srcs[4] = {w1, w2, w3, wc};
    float*       dsts[4] = {q1, q2, q3, qc};
    const int    ns[4]   = {32*3*9, 64*32*9, 128*64*9, 10*128};
    const int t = blockIdx.y;
    const float* s = srcs[t];
    float*       d = dsts[t];
    const int    N = ns[t];
    const float sc = fmaxf(__uint_as_float(maxb[t]), 1e-8f);  // qmax = 2^(2-1)-1 = 1
    for (int i = blockIdx.x * 256 + threadIdx.x; i < N; i += 16 * 256)
        d[i] = rintf(s[i] / sc) * sc;
}

// Per (slice-of-16-co, ci): (a) 16-bit pair mask (bit c set iff
// co=slice*16+c has any nonzero at this ci), stored as uint; (b) padded coef
// table cw: 12-float (16B-aligned) rows, row index (slice*CIN+ci)*16+c,
// coefs k=0..8 then 3 zeros.
__global__ __launch_bounds__(256)
void build_masks(const float* __restrict__ qw, int Co, int CIN,
                 unsigned* __restrict__ masks, float* __restrict__ cw) {
    const int nsl = Co / 16;
    const int nrow = nsl * CIN;
    const int t = threadIdx.x;
    for (int i = t; i < nrow; i += 256) {
        const int sl = i / CIN, ci = i - sl * CIN;
        unsigned m = 0;
        for (int c = 0; c < 16; ++c) {
            const int co = sl * 16 + c;
            bool nz = false;
            for (int k = 0; k < 9; ++k)
                nz |= (qw[(co * CIN + ci) * 9 + k] != 0.f);
            if (nz) m |= (1u << c);
        }
        masks[i] = m;
    }
    const int npair = nrow * 16;
    for (int pidx = t; pidx < npair; pidx += 256) {
        const int c = pidx & 15, i = pidx >> 4;
        const int sl = i / CIN, ci = i - sl * CIN;
        const int co = sl * 16 + c;
        float* dst = cw + (size_t)pidx * 12;
        #pragma unroll
        for (int k = 0; k < 9; ++k)
            dst[k] = qw[(co * CIN + ci) * 9 + k];
        dst[9] = dst[10] = dst[11] = 0.f;
    }
}

// Sparse fused conv3x3(pad=1) + maxpool2 + quant_act — NO LDS, NO BARRIERS.
// Block 16x16 threads over a 16x16 pooled tile; blockIdx.z = batch x slice.
// Per ci (skipped if slice mask empty): each thread loads its 4x4 patch
// directly from global (4x dwordx4 fast path, per-element at edges), then
// mask-guarded dense 36-FMA bodies with scalar coefs.
template<int CIN, int Co>
__global__ __launch_bounds__(256, 4)
void conv_direct(const float* __restrict__ in, const unsigned* __restrict__ masks,
                 const float* __restrict__ cw,
                 const float* __restrict__ alpha_p, float* __restrict__ out,
                 int H, int W) {
    constexpr int NSL = Co / 16;
    const int PH = H >> 1, PW = W >> 1;
    const int tx = threadIdx.x, ty = threadIdx.y;
    const int b     = blockIdx.z / NSL;
    const int slice = blockIdx.z % NSL;          // SGPR (blockIdx is scalar)
    const int px = blockIdx.x * 16 + tx;
    const int py = blockIdx.y * 16 + ty;
    const int x0 = 2 * px - 1;                   // patch col origin
    const size_t HW = (size_t)H * W;
    const float* inB = in + (size_t)b * CIN * HW;

    // Row geometry hoisted once.
    bool rok[4]; int rowoff[4];
    #pragma unroll
    for (int r = 0; r < 4; ++r) {
        const int gy = 2 * py - 1 + r;
        rok[r] = (gy >= 0) && (gy < H);
        rowoff[r] = rok[r] ? gy * W : 0;
    }
    const bool colfast = (x0 >= 0) && (x0 + 3 < W);

    float acc[16][4];
    #pragma unroll
    for (int c = 0; c < 16; ++c)
        #pragma unroll
        for (int q = 0; q < 4; ++q) acc[c][q] = 0.f;

    const unsigned* msl = masks + (size_t)slice * CIN;
    const float*   cwsl = cw + (size_t)slice * CIN * 16 * 12;

    #pragma unroll 2
    for (int ci = 0; ci < CIN; ++ci) {
        const unsigned m16 = msl[ci];            // uniform -> s_load
        if (!m16) continue;                      // uniform skip (rare)
        const float* inC = inB + (size_t)ci * HW;

        // 4x4 patch straight from global: all nine k-stencils for 2x2 outputs.
        float p[4][4];
        #pragma unroll
        for (int r = 0; r < 4; ++r) {
            if (rok[r] && colfast) {             // interior: one dwordx4
                const vfloat4 q = *(const vfloat4*)(inC + rowoff[r] + x0);
                p[r][0] = q.x; p[r][1] = q.y; p[r][2] = q.z; p[r][3] = q.w;
            } else {                             // edges: per-element guarded
                #pragma unroll
                for (int j = 0; j < 4; ++j) {
                    const int gx = x0 + j;
                    p[r][j] = (rok[r] && gx >= 0 && gx < W)
                              ? inC[rowoff[r] + gx] : 0.f;
                }
            }
        }

        const float* cwr = cwsl + (size_t)ci * 16 * 12;
        #pragma unroll
        for (int c = 0; c < 16; ++c) {
            if (m16 & (1u << c)) {               // uniform s_bitcmp+s_cbranch
                const float* wp = cwr + c * 12;  // 16B-aligned row
                #pragma unroll
                for (int k = 0; k < 9; ++k) {
                    const float w = wp[k];       // uniform -> s_load
                    acc[c][0] = fmaf(w, p[k/3    ][k%3    ], acc[c][0]);
                    acc[c][1] = fmaf(w, p[k/3    ][k%3 + 1], acc[c][1]);
                    acc[c][2] = fmaf(w, p[k/3 + 1][k%3    ], acc[c][2]);
                    acc[c][3] = fmaf(w, p[k/3 + 1][k%3 + 1], acc[c][3]);
                }
            }
        }
    }

    if (py < PH && px < PW) {
        const float alpha = *alpha_p;
        const float scale = alpha / 3.0f;        // 2^ABITS - 1 = 3
        const int co0 = slice * 16;
        #pragma unroll
        for (int c = 0; c < 16; ++c) {
            const float m = fmaxf(fmaxf(acc[c][0], acc[c][1]),
                                  fmaxf(acc[c][2], acc[c][3]));
            const float y = fminf(fmaxf(m, 0.f), alpha);
            out[(((size_t)b * Co + co0 + c) * PH + py) * PW + px] =
                rintf(y / scale) * scale;
        }
    }
}

// One wave per (channel, batch): global max over 28x28.
__global__ __launch_bounds__(64)
void gmax_kernel(const float* __restrict__ h3, float* __restrict__ g) {
    const int c = blockIdx.x, b = blockIdx.y;
    const float* p = h3 + ((size_t)b * 128 + c) * 784;
    float m = -INFINITY;
    for (int i = threadIdx.x; i < 784; i += 64) m = fmaxf(m, p[i]);
    #pragma unroll
    for (int o = 32; o > 0; o >>= 1) m = fmaxf(m, __shfl_down(m, o));
    if (threadIdx.x == 0) g[b * 128 + c] = m;
}

// 1x1 conv 128->10 per batch (same k-ascending FMA order as round 1).
__global__ __launch_bounds__(128)
void classify_kernel(const float* __restrict__ g, const float* __restrict__ qwc,
                     float* __restrict__ out) {
    const int b = blockIdx.x;
    __shared__ float gg[128];
    gg[threadIdx.x] = g[b * 128 + threadIdx.x];
    __syncthreads();
    if (threadIdx.x < 10) {
        float s = 0.f;
        for (int k = 0; k < 128; ++k) s += qwc[threadIdx.x * 128 + k] * gg[k];
        out[b * 10 + threadIdx.x] = s;
    }
}

extern "C" void kernel_launch(void* const* d_in, const int* in_sizes, int n_in,
                              void* d_out, int out_size, void* d_ws, size_t ws_size,
                              hipStream_t stream) {
    const float* x  = (const float*)d_in[0];
    const float* w1 = (const float*)d_in[1];
    const float* w2 = (const float*)d_in[2];
    const float* w3 = (const float*)d_in[3];
    const float* wc = (const float*)d_in[4];
    const float* a1 = (const float*)d_in[5];
    const float* a2 = (const float*)d_in[6];
    const float* a3 = (const float*)d_in[7];

    float* ws = (float*)d_ws;
    size_t o = 0;
    float* qw1 = ws + o; o += 32 * 3 * 9;           // 864
    float* qw2 = ws + o; o += 64 * 32 * 9;          // 18432
    float* qw3 = ws + o; o += 128 * 64 * 9;         // 73728
    float* qwc = ws + o; o += 10 * 128;             // 1280
    unsigned* maxb = (unsigned*)(ws + o); o += 4;
    float* g   = ws + o; o += 32 * 128;             // 4096
    unsigned* mk1 = (unsigned*)(ws + o); o += 8;    // 2 sl * 3 ci = 6
    unsigned* mk2 = (unsigned*)(ws + o); o += 128;  // 4 sl * 32 ci
    unsigned* mk3 = (unsigned*)(ws + o); o += 512;  // 8 sl * 64 ci
    float* cw1 = ws + o; o += 2UL * 3 * 16 * 12;    //  1152 (o%4==0: 16B ok)
    float* cw2 = ws + o; o += 4UL * 32 * 16 * 12;   // 24576
    float* cw3 = ws + o; o += 8UL * 64 * 16 * 12;   // 98304
    float* h1p = ws + o; o += 32UL * 32 * 112 * 112;
    float* h2p = ws + o; o += 32UL * 64 * 56 * 56;
    float* h3p = ws + o; o += 32UL * 128 * 28 * 28;

    prep_zero<<<1, 64, 0, stream>>>(maxb);
    prep_absmax<<<dim3(16, 4), 256, 0, stream>>>(w1, w2, w3, wc, maxb);
    prep_quant<<<dim3(16, 4), 256, 0, stream>>>(w1, w2, w3, wc, maxb,
                                                qw1, qw2, qw3, qwc);
    build_masks<<<1, 256, 0, stream>>>(qw1, 32, 3,  mk1, cw1);
    build_masks<<<1, 256, 0, stream>>>(qw2, 64, 32, mk2, cw2);
    build_masks<<<1, 256, 0, stream>>>(qw3, 128, 64, mk3, cw3);

    // conv1: 3->32, pooled 112x112. 7x7 tiles, z = 32 b * 2 slices.
    conv_direct<3, 32><<<dim3(7, 7, 32 * 2), dim3(16, 16), 0, stream>>>(
        x, mk1, cw1, a1, h1p, 224, 224);
    // conv2: 32->64, pooled 56x56. 4x4 tiles, z = 32 b * 4 slices.
    conv_direct<32, 64><<<dim3(4, 4, 32 * 4), dim3(16, 16), 0, stream>>>(
        h1p, mk2, cw2, a2, h2p, 112, 112);
    // conv3: 64->128, pooled 28x28. 2x2 tiles, z = 32 b * 8 slices.
    conv_direct<64, 128><<<dim3(2, 2, 32 * 8), dim3(16, 16), 0, stream>>>(
        h2p, mk3, cw3, a3, h3p, 56, 56);

    gmax_kernel<<<dim3(128, 32), 64, 0, stream>>>(h3p, g);
    classify_kernel<<<32, 128, 0, stream>>>(g, qwc, (float*)d_out);
}